// Round 2
// baseline (4954.876 us; speedup 1.0000x reference)
//
#include <hip/hip_runtime.h>
#include <math.h>

#define NB 256
#define NS 100
#define ND 512
#define NH 8
#define NDFF 2048
#define NL 4
#define NM (NB * NS)  // 25600 tokens

typedef unsigned short u16;
typedef unsigned short u16x4 __attribute__((ext_vector_type(4)));
typedef unsigned short u16x8 __attribute__((ext_vector_type(8)));
typedef __bf16 bf16x8 __attribute__((ext_vector_type(8)));
typedef float f32x4 __attribute__((ext_vector_type(4)));

__device__ __forceinline__ float b2f(u16 u) {
  unsigned v = ((unsigned)u) << 16;
  return __builtin_bit_cast(float, v);
}
__device__ __forceinline__ u16 f2b(float f) {
  unsigned u = __builtin_bit_cast(unsigned, f);
  u += 0x7fffu + ((u >> 16) & 1u);
  return (u16)(u >> 16);
}

// ---------------------------------------------------------------------------
// f32 -> bf16 cast (weights), 4 elems/thread
// ---------------------------------------------------------------------------
__global__ __launch_bounds__(256) void cast_kernel(const float* __restrict__ in,
                                                   u16* __restrict__ out) {
  int i = blockIdx.x * 256 + threadIdx.x;
  float4 v = ((const float4*)in)[i];
  u16x4 o = {f2b(v.x), f2b(v.y), f2b(v.z), f2b(v.w)};
  ((u16x4*)out)[i] = o;
}

// ---------------------------------------------------------------------------
// x = emb + PE ; writes f32 x and bf16 mirror xb
// ---------------------------------------------------------------------------
__global__ __launch_bounds__(256) void add_pe_kernel(const float* __restrict__ emb,
                                                     float* __restrict__ x,
                                                     u16* __restrict__ xb) {
  int idx = blockIdx.x * 256 + threadIdx.x;
  int d = idx & (ND - 1);
  int s = (idx >> 9) % NS;
  float ang = (float)s * (float)(d & ~1) * (-4.6051701859880914f / (float)ND);
  float pe = (d & 1) ? __cosf(ang) : __sinf(ang);
  float v = emb[idx] + pe;
  x[idx] = v;
  xb[idx] = f2b(v);
}

// ---------------------------------------------------------------------------
// C = A @ W^T + bias (optional ReLU), A: MxK bf16, W: NxK bf16.
// MFMA 16x16x32 bf16. 128x128 tile, BK=32, 256 thr = 4 waves (2x2 of 64x64).
// LDS rows padded to 40 elems (80 B) -> 2-way bank aliasing (free).
// A-frag & B-frag: lane l reads row (l&15) elems [(l>>4)*8 .. +7]  (NT idiom).
// C/D: col = lane&15, row = (lane>>4)*4 + j   [verified m89/m91].
// ---------------------------------------------------------------------------
template <bool RELU, bool OUTBF16>
__global__ __launch_bounds__(256) void gemm_mfma(const u16* __restrict__ A,
                                                 const u16* __restrict__ W,
                                                 const float* __restrict__ bias,
                                                 float* __restrict__ Cf,
                                                 u16* __restrict__ Cb,
                                                 int N, int K) {
  __shared__ u16 As[128 * 40];
  __shared__ u16 Ws[128 * 40];
  const int t = threadIdx.x;
  const int lane = t & 63;
  const int wave = t >> 6;
  const int wr = wave >> 1, wc = wave & 1;
  const int m0 = blockIdx.y * 128, n0 = blockIdx.x * 128;
  const int r = t >> 2, cb = t & 3;
  const u16* pA = A + (size_t)(m0 + r) * K + cb * 8;
  const u16* pW = W + (size_t)(n0 + r) * K + cb * 8;
  const int ldsoff = r * 40 + cb * 8;

  f32x4 acc[4][4];
#pragma unroll
  for (int m = 0; m < 4; ++m)
#pragma unroll
    for (int n = 0; n < 4; ++n) acc[m][n] = (f32x4){0.f, 0.f, 0.f, 0.f};

  const int lg = lane >> 4;  // k-group 0..3
  const int li = lane & 15;  // fragment row/col
  const int aoff = (wr * 64 + li) * 40 + lg * 8;
  const int boff = (wc * 64 + li) * 40 + lg * 8;

  for (int k0 = 0; k0 < K; k0 += 32) {
    u16x8 a0 = *(const u16x8*)(pA + k0);
    u16x8 a1 = *(const u16x8*)(pA + (size_t)64 * K + k0);
    u16x8 w0 = *(const u16x8*)(pW + k0);
    u16x8 w1 = *(const u16x8*)(pW + (size_t)64 * K + k0);
    __syncthreads();  // previous tile fully consumed
    *(u16x8*)&As[ldsoff] = a0;
    *(u16x8*)&As[ldsoff + 64 * 40] = a1;
    *(u16x8*)&Ws[ldsoff] = w0;
    *(u16x8*)&Ws[ldsoff + 64 * 40] = w1;
    __syncthreads();
    bf16x8 af[4], bf_[4];
#pragma unroll
    for (int m = 0; m < 4; ++m)
      af[m] = __builtin_bit_cast(bf16x8, *(const u16x8*)&As[aoff + m * 16 * 40]);
#pragma unroll
    for (int n = 0; n < 4; ++n)
      bf_[n] = __builtin_bit_cast(bf16x8, *(const u16x8*)&Ws[boff + n * 16 * 40]);
#pragma unroll
    for (int m = 0; m < 4; ++m)
#pragma unroll
      for (int n = 0; n < 4; ++n)
        acc[m][n] = __builtin_amdgcn_mfma_f32_16x16x32_bf16(af[m], bf_[n], acc[m][n], 0, 0, 0);
  }

#pragma unroll
  for (int m = 0; m < 4; ++m) {
    int row = m0 + wr * 64 + m * 16 + lg * 4;
#pragma unroll
    for (int n = 0; n < 4; ++n) {
      int col = n0 + wc * 64 + n * 16 + li;
      float bv = bias[col];
#pragma unroll
      for (int j = 0; j < 4; ++j) {
        float v = acc[m][n][j] + bv;
        if (RELU) v = fmaxf(v, 0.f);
        if (OUTBF16) Cb[(size_t)(row + j) * N + col] = f2b(v);
        else Cf[(size_t)(row + j) * N + col] = v;
      }
    }
  }
}

// ---------------------------------------------------------------------------
// Attention per (b,h); grid (BC*8, 5): blockIdx.y picks 20 queries.
// qkv bf16 (rows of 1536: q|k|v), out bf16. 3 barriers per query.
// ---------------------------------------------------------------------------
__global__ __launch_bounds__(128) void attn_kernel(const u16* __restrict__ qkv,
                                                   const int* __restrict__ mask,
                                                   u16* __restrict__ out) {
  const int bh = blockIdx.x;
  const int b = bh >> 3, h = bh & 7;
  __shared__ float Ks[NS][65];
  __shared__ float Vs[NS][65];
  __shared__ float qv[64];
  __shared__ float sc[128];
  __shared__ float red[4];
  __shared__ float mbias[NS];
  const int t = threadIdx.x;
  const u16* base = qkv + (size_t)b * NS * 1536 + h * 64;
  for (int e = t; e < NS * 16; e += 128) {
    int s = e >> 4, d = (e & 15) << 2;
    u16x4 kk = *(const u16x4*)(base + (size_t)s * 1536 + 512 + d);
    u16x4 vv = *(const u16x4*)(base + (size_t)s * 1536 + 1024 + d);
    Ks[s][d + 0] = b2f(kk[0]); Ks[s][d + 1] = b2f(kk[1]);
    Ks[s][d + 2] = b2f(kk[2]); Ks[s][d + 3] = b2f(kk[3]);
    Vs[s][d + 0] = b2f(vv[0]); Vs[s][d + 1] = b2f(vv[1]);
    Vs[s][d + 2] = b2f(vv[2]); Vs[s][d + 3] = b2f(vv[3]);
  }
  if (t < NS) mbias[t] = (mask[b * NS + t] == 0) ? -INFINITY : 0.f;
  __syncthreads();
  const int qlo = blockIdx.y * 20;
  for (int qi = qlo; qi < qlo + 20; ++qi) {
    if (t < 64) qv[t] = b2f(base[(size_t)qi * 1536 + t]);
    __syncthreads();  // A: qv ready (also guards qv/sc reuse)
    float sv = -INFINITY;
    if (t < NS) {
      float a = 0.f;
#pragma unroll
      for (int d = 0; d < 64; ++d) a += qv[d] * Ks[t][d];
      sv = a * 0.125f + mbias[t];
    }
    float m_ = sv;
#pragma unroll
    for (int off = 32; off; off >>= 1) m_ = fmaxf(m_, __shfl_xor(m_, off));
    if ((t & 63) == 0) red[t >> 6] = m_;
    __syncthreads();  // B
    float mx = fmaxf(red[0], red[1]);
    float e = (t < NS) ? __expf(sv - mx) : 0.f;
    sc[t] = e;
    float s_ = e;
#pragma unroll
    for (int off = 32; off; off >>= 1) s_ += __shfl_xor(s_, off);
    if ((t & 63) == 0) red[2 + (t >> 6)] = s_;
    __syncthreads();  // C: sc + sums ready
    if (t < 64) {
      float inv = 1.f / (red[2] + red[3]);
      float a = 0.f;
#pragma unroll 4
      for (int s = 0; s < NS; ++s) a += sc[s] * Vs[s][t];
      out[((size_t)b * NS + qi) * ND + h * 64 + t] = f2b(a * inv);
    }
  }
}

// ---------------------------------------------------------------------------
// x = LN(x + r) * g + b ; writes f32 x and bf16 xb. One block per token.
// ---------------------------------------------------------------------------
__global__ __launch_bounds__(256) void add_ln_kernel(float* __restrict__ x,
                                                     u16* __restrict__ xb,
                                                     const float* __restrict__ rsd,
                                                     const float* __restrict__ g,
                                                     const float* __restrict__ bb) {
  int row = blockIdx.x;
  int t = threadIdx.x;
  size_t base = (size_t)row * ND;
  float v0 = x[base + t] + rsd[base + t];
  float v1 = x[base + t + 256] + rsd[base + t + 256];
  float s = v0 + v1;
  float q = v0 * v0 + v1 * v1;
  for (int off = 32; off; off >>= 1) {
    s += __shfl_down(s, off);
    q += __shfl_down(q, off);
  }
  __shared__ float sbuf[8];
  int wid = t >> 6, lane = t & 63;
  if (lane == 0) { sbuf[wid] = s; sbuf[4 + wid] = q; }
  __syncthreads();
  if (t == 0) {
    float ts = sbuf[0] + sbuf[1] + sbuf[2] + sbuf[3];
    float tq = sbuf[4] + sbuf[5] + sbuf[6] + sbuf[7];
    float mean = ts * (1.f / (float)ND);
    float var = tq * (1.f / (float)ND) - mean * mean;
    sbuf[0] = mean;
    sbuf[1] = rsqrtf(var + 1e-5f);
  }
  __syncthreads();
  float mean = sbuf[0], rstd = sbuf[1];
  float o0 = (v0 - mean) * rstd * g[t] + bb[t];
  float o1 = (v1 - mean) * rstd * g[t + 256] + bb[t + 256];
  x[base + t] = o0;
  x[base + t + 256] = o1;
  xb[base + t] = f2b(o0);
  xb[base + t + 256] = f2b(o1);
}

// ---------------------------------------------------------------------------
// w2sum[d] = sum_o attn_w[o, D + d]  (s_q and attn_b cancel in the softmax)
// ---------------------------------------------------------------------------
__global__ __launch_bounds__(64) void w2sum_kernel(const float* __restrict__ attn_w,
                                                   float* __restrict__ w2sum) {
  int d = blockIdx.x * 64 + threadIdx.x;
  float s = 0.f;
  for (int o = 0; o < ND; ++o) s += attn_w[(size_t)o * 1024 + 512 + d];
  w2sum[d] = s;
}

// ---------------------------------------------------------------------------
// Pooling head (f32 x): p = softmax_s(mask ? x.w2sum : -inf); out = p @ x
// ---------------------------------------------------------------------------
__global__ __launch_bounds__(128) void pool_kernel(const float* __restrict__ x,
                                                   const int* __restrict__ mask,
                                                   const float* __restrict__ w2sum,
                                                   float* __restrict__ out) {
  int b = blockIdx.x;
  int t = threadIdx.x;
  __shared__ float wsm[ND];
  __shared__ float sc[128];
  __shared__ float red[128];
  for (int d = t; d < ND; d += 128) wsm[d] = w2sum[d];
  __syncthreads();
  float sv = -INFINITY;
  if (t < NS && mask[b * NS + t] != 0) {
    const float* xr = x + ((size_t)b * NS + t) * ND;
    float acc = 0.f;
    for (int d = 0; d < ND; ++d) acc += xr[d] * wsm[d];
    sv = acc;
  }
  red[t] = sv;
  __syncthreads();
  for (int off = 64; off; off >>= 1) {
    if (t < off) red[t] = fmaxf(red[t], red[t + off]);
    __syncthreads();
  }
  float mx = red[0];
  __syncthreads();
  float e = (t < NS) ? __expf(sv - mx) : 0.f;
  sc[t] = e;
  red[t] = e;
  __syncthreads();
  for (int off = 64; off; off >>= 1) {
    if (t < off) red[t] += red[t + off];
    __syncthreads();
  }
  float inv = 1.f / red[0];
  for (int d = t; d < ND; d += 128) {
    float acc = 0.f;
    for (int s = 0; s < NS; ++s) acc += sc[s] * x[((size_t)b * NS + s) * ND + d];
    out[(size_t)b * ND + d] = acc * inv;
  }
}

// ---------------------------------------------------------------------------
extern "C" void kernel_launch(void* const* d_in, const int* in_sizes, int n_in,
                              void* d_out, int out_size, void* d_ws, size_t ws_size,
                              hipStream_t stream) {
  const int* mask = (const int*)d_in[0];
  const float* emb = (const float*)d_in[1];
  const float* in_proj_w = (const float*)d_in[2];
  const float* in_proj_b = (const float*)d_in[3];
  const float* out_proj_w = (const float*)d_in[4];
  const float* out_proj_b = (const float*)d_in[5];
  const float* lin1_w = (const float*)d_in[6];
  const float* lin1_b = (const float*)d_in[7];
  const float* lin2_w = (const float*)d_in[8];
  const float* lin2_b = (const float*)d_in[9];
  const float* ln1_w = (const float*)d_in[10];
  const float* ln1_b = (const float*)d_in[11];
  const float* ln2_w = (const float*)d_in[12];
  const float* ln2_b = (const float*)d_in[13];
  const float* attn_w = (const float*)d_in[14];
  // d_in[15] = attn_b: constant over the softmax axis -> cancels; unused.

  char* wsb = (char*)d_ws;
  size_t off = 0;
  auto alloc = [&](size_t bytes) -> char* {
    char* p = wsb + off;
    off += (bytes + 255) & ~(size_t)255;
    return p;
  };
  float* x   = (float*)alloc((size_t)NM * ND * 4);
  u16* xb    = (u16*)alloc((size_t)NM * ND * 2);
  u16* wqkv  = (u16*)alloc((size_t)NL * 1536 * 512 * 2);
  u16* wout  = (u16*)alloc((size_t)NL * 512 * 512 * 2);
  u16* w1b   = (u16*)alloc((size_t)NL * 2048 * 512 * 2);
  u16* w2b   = (u16*)alloc((size_t)NL * 512 * 2048 * 2);
  float* w2s = (float*)alloc(ND * 4);
  size_t fixedEnd = off;

  // Largest batch-chunk whose buffers fit in ws_size (Mc must be /128: BC%32==0)
  int BC = 32;
  const int cands[4] = {256, 128, 64, 32};
  auto alup = [](size_t b) { return (b + 255) & ~(size_t)255; };
  for (int ci = 0; ci < 4; ++ci) {
    size_t Mc = (size_t)cands[ci] * NS;
    size_t need = fixedEnd + alup(Mc * 2048 * 2) + alup(Mc * 512 * 2) + alup(Mc * 512 * 4);
    if (need <= ws_size) { BC = cands[ci]; break; }
  }
  const size_t Mc = (size_t)BC * NS;
  u16* big    = (u16*)alloc(Mc * 2048 * 2);  // qkv (Mc x 1536) / h1 (Mc x 2048)
  u16* bufA   = (u16*)alloc(Mc * 512 * 2);   // attention out
  float* bufT = (float*)alloc(Mc * 512 * 4); // proj / ff out (f32 for residual)

  cast_kernel<<<NL * 1536 * 512 / 1024, 256, 0, stream>>>(in_proj_w, wqkv);
  cast_kernel<<<NL * 512 * 512 / 1024, 256, 0, stream>>>(out_proj_w, wout);
  cast_kernel<<<NL * 2048 * 512 / 1024, 256, 0, stream>>>(lin1_w, w1b);
  cast_kernel<<<NL * 512 * 2048 / 1024, 256, 0, stream>>>(lin2_w, w2b);
  add_pe_kernel<<<NM * ND / 256, 256, 0, stream>>>(emb, x, xb);

  const int NC = NB / BC;
  for (int i = 0; i < NL; ++i) {
    for (int c = 0; c < NC; ++c) {
      float* xc = x + (size_t)c * Mc * ND;
      u16* xbc = xb + (size_t)c * Mc * ND;
      gemm_mfma<false, true><<<dim3(1536 / 128, Mc / 128), 256, 0, stream>>>(
          xbc, wqkv + (size_t)i * 1536 * 512, in_proj_b + i * 1536, nullptr, big, 1536, 512);
      attn_kernel<<<dim3(BC * NH, 5), 128, 0, stream>>>(big, mask + (size_t)c * BC * NS, bufA);
      gemm_mfma<false, false><<<dim3(512 / 128, Mc / 128), 256, 0, stream>>>(
          bufA, wout + (size_t)i * 512 * 512, out_proj_b + i * 512, bufT, nullptr, 512, 512);
      add_ln_kernel<<<Mc, 256, 0, stream>>>(xc, xbc, bufT, ln1_w + i * 512, ln1_b + i * 512);
      gemm_mfma<true, true><<<dim3(2048 / 128, Mc / 128), 256, 0, stream>>>(
          xbc, w1b + (size_t)i * 2048 * 512, lin1_b + i * 2048, nullptr, big, 2048, 512);
      gemm_mfma<false, false><<<dim3(512 / 128, Mc / 128), 256, 0, stream>>>(
          big, w2b + (size_t)i * 512 * 2048, lin2_b + i * 512, bufT, nullptr, 512, 2048);
      add_ln_kernel<<<Mc, 256, 0, stream>>>(xc, xbc, bufT, ln2_w + i * 512, ln2_b + i * 512);
    }
  }

  w2sum_kernel<<<ND / 64, 64, 0, stream>>>(attn_w, w2s);
  pool_kernel<<<NB, 128, 0, stream>>>(x, mask, w2s, (float*)d_out);
}

// Round 3
// 2386.526 us; speedup vs baseline: 2.0762x; 2.0762x over previous
//
#include <hip/hip_runtime.h>
#include <math.h>

#define NB 256
#define NS 100
#define ND 512
#define NH 8
#define NDFF 2048
#define NL 4
#define NM (NB * NS)  // 25600 tokens

typedef unsigned short u16;
typedef unsigned short u16x4 __attribute__((ext_vector_type(4)));
typedef unsigned short u16x8 __attribute__((ext_vector_type(8)));
typedef __bf16 bf16x8 __attribute__((ext_vector_type(8)));
typedef float f32x4 __attribute__((ext_vector_type(4)));

__device__ __forceinline__ float b2f(u16 u) {
  unsigned v = ((unsigned)u) << 16;
  return __builtin_bit_cast(float, v);
}
__device__ __forceinline__ u16 f2b(float f) {
  unsigned u = __builtin_bit_cast(unsigned, f);
  u += 0x7fffu + ((u >> 16) & 1u);
  return (u16)(u >> 16);
}
// async global->LDS, 16B per lane; LDS dest is wave-uniform base (HW adds lane*16)
__device__ __forceinline__ void gload_lds16(const void* g, void* l) {
  __builtin_amdgcn_global_load_lds(
      (const __attribute__((address_space(1))) unsigned int*)g,
      (__attribute__((address_space(3))) unsigned int*)l, 16, 0, 0);
}

// ---------------------------------------------------------------------------
// f32 -> bf16 cast (weights)
// ---------------------------------------------------------------------------
__global__ __launch_bounds__(256) void cast_kernel(const float* __restrict__ in,
                                                   u16* __restrict__ out) {
  int i = blockIdx.x * 256 + threadIdx.x;
  float4 v = ((const float4*)in)[i];
  u16x4 o = {f2b(v.x), f2b(v.y), f2b(v.z), f2b(v.w)};
  ((u16x4*)out)[i] = o;
}

// ---------------------------------------------------------------------------
// x = emb + PE ; writes f32 x and bf16 mirror xb
// ---------------------------------------------------------------------------
__global__ __launch_bounds__(256) void add_pe_kernel(const float* __restrict__ emb,
                                                     float* __restrict__ x,
                                                     u16* __restrict__ xb) {
  int idx = blockIdx.x * 256 + threadIdx.x;
  int d = idx & (ND - 1);
  int s = (idx >> 9) % NS;
  float ang = (float)s * (float)(d & ~1) * (-4.6051701859880914f / (float)ND);
  float pe = (d & 1) ? __cosf(ang) : __sinf(ang);
  float v = emb[idx] + pe;
  x[idx] = v;
  xb[idx] = f2b(v);
}

// ---------------------------------------------------------------------------
// C = A @ W^T + bias (optional ReLU). A: MxK bf16, W: NxK bf16.
// m97 structure: 128x128 tile, BK=32, 4 waves (2x2), linear LDS [128][32],
// global_load_lds width=16 staging, 2 barriers per K-step.
// Chunk c (16 rows) at LDS elem c*512; lane l writes elem 8l = (l/4)*32+(l%4)*8.
// C/D: col = lane&15, row = (lane>>4)*4 + j   [verified m89/m91 + round 2 pass]
// ---------------------------------------------------------------------------
template <bool RELU, bool OUTBF16>
__global__ __launch_bounds__(256) void gemm_mfma(const u16* __restrict__ A,
                                                 const u16* __restrict__ W,
                                                 const float* __restrict__ bias,
                                                 float* __restrict__ Cf,
                                                 u16* __restrict__ Cb,
                                                 int N, int K) {
  __shared__ u16 As[128 * 32];
  __shared__ u16 Ws[128 * 32];
  const int t = threadIdx.x;
  const int lane = t & 63;
  const int wave = t >> 6;
  const int wr = wave >> 1, wc = wave & 1;
  const int m0 = blockIdx.y * 128, n0 = blockIdx.x * 128;

  // staging: wave stages chunks {wave, wave+4} of both A and W
  const int srow = wave * 16 + (lane >> 2);
  const int scol = (lane & 3) * 8;
  const u16* gA0 = A + (size_t)(m0 + srow) * K + scol;
  const u16* gA1 = gA0 + (size_t)64 * K;
  const u16* gW0 = W + (size_t)(n0 + srow) * K + scol;
  const u16* gW1 = gW0 + (size_t)64 * K;
  u16* lA0 = As + wave * 512;
  u16* lA1 = As + (wave + 4) * 512;
  u16* lW0 = Ws + wave * 512;
  u16* lW1 = Ws + (wave + 4) * 512;

  f32x4 acc[4][4];
#pragma unroll
  for (int m = 0; m < 4; ++m)
#pragma unroll
    for (int n = 0; n < 4; ++n) acc[m][n] = (f32x4){0.f, 0.f, 0.f, 0.f};

  const int lg = lane >> 4;  // k-group 0..3
  const int li = lane & 15;  // fragment row/col
  const int abase = (wr * 64 + li) * 32 + lg * 8;
  const int bbase = (wc * 64 + li) * 32 + lg * 8;

  for (int k0 = 0; k0 < K; k0 += 32) {
    __syncthreads();  // previous tile fully consumed
    gload_lds16(gA0 + k0, lA0);
    gload_lds16(gA1 + k0, lA1);
    gload_lds16(gW0 + k0, lW0);
    gload_lds16(gW1 + k0, lW1);
    __syncthreads();  // drains vmcnt -> tile resident
    bf16x8 af[4], bf_[4];
#pragma unroll
    for (int m = 0; m < 4; ++m)
      af[m] = __builtin_bit_cast(bf16x8, *(const u16x8*)&As[abase + m * 512]);
#pragma unroll
    for (int n = 0; n < 4; ++n)
      bf_[n] = __builtin_bit_cast(bf16x8, *(const u16x8*)&Ws[bbase + n * 512]);
#pragma unroll
    for (int m = 0; m < 4; ++m)
#pragma unroll
      for (int n = 0; n < 4; ++n)
        acc[m][n] = __builtin_amdgcn_mfma_f32_16x16x32_bf16(af[m], bf_[n], acc[m][n], 0, 0, 0);
  }

#pragma unroll
  for (int m = 0; m < 4; ++m) {
    int row = m0 + wr * 64 + m * 16 + lg * 4;
#pragma unroll
    for (int n = 0; n < 4; ++n) {
      int col = n0 + wc * 64 + n * 16 + li;
      float bv = bias[col];
#pragma unroll
      for (int j = 0; j < 4; ++j) {
        float v = acc[m][n][j] + bv;
        if (RELU) v = fmaxf(v, 0.f);
        if (OUTBF16) Cb[(size_t)(row + j) * N + col] = f2b(v);
        else Cf[(size_t)(row + j) * N + col] = v;
      }
    }
  }
}

// ---------------------------------------------------------------------------
// Attention per (b,h), thread-per-query. 128 threads, ONE barrier.
// K bf16 in LDS (decode on read, broadcast), V f32 (broadcast), private score
// row sc[q][0..99] (pad 101 -> conflict-free per-lane access). Softmax fully
// thread-local; exp fused into PV pass.
// ---------------------------------------------------------------------------
__global__ __launch_bounds__(128) void attn_kernel(const u16* __restrict__ qkv,
                                                   const int* __restrict__ mask,
                                                   u16* __restrict__ out) {
  const int bh = blockIdx.x;
  const int b = bh >> 3, h = bh & 7;
  __shared__ u16 Ksb[NS * 64];        // 12.8 KB
  __shared__ float Vs[NS * 64];       // 25.6 KB
  __shared__ float sc[NS * 101];      // 40.4 KB
  __shared__ float mb[NS + 4];
  const int t = threadIdx.x;
  const u16* base = qkv + (size_t)b * NS * 1536 + h * 64;

  for (int e = t; e < NS * 16; e += 128) {
    int s = e >> 4, d4 = (e & 15) << 2;
    *(u16x4*)&Ksb[s * 64 + d4] = *(const u16x4*)(base + (size_t)s * 1536 + 512 + d4);
    u16x4 vv = *(const u16x4*)(base + (size_t)s * 1536 + 1024 + d4);
    Vs[s * 64 + d4 + 0] = b2f(vv[0]);
    Vs[s * 64 + d4 + 1] = b2f(vv[1]);
    Vs[s * 64 + d4 + 2] = b2f(vv[2]);
    Vs[s * 64 + d4 + 3] = b2f(vv[3]);
  }
  if (t < NS) mb[t] = (mask[b * NS + t] == 0) ? -INFINITY : 0.f;

  // q for this thread's query, scale 1/8 folded in
  float qf[64];
  if (t < NS) {
    const u16* gq = base + (size_t)t * 1536;
#pragma unroll
    for (int j = 0; j < 8; ++j) {
      u16x8 qq = *(const u16x8*)(gq + j * 8);
#pragma unroll
      for (int e = 0; e < 8; ++e) qf[j * 8 + e] = b2f(qq[e]) * 0.125f;
    }
  }
  __syncthreads();  // staging complete (the only barrier)

  if (t < NS) {
    float* myrow = &sc[t * 101];
    float rmax = -INFINITY;
    for (int s = 0; s < NS; ++s) {
      float a0 = 0.f, a1 = 0.f, a2 = 0.f, a3 = 0.f;
#pragma unroll
      for (int j = 0; j < 8; ++j) {
        u16x8 kk = *(const u16x8*)&Ksb[s * 64 + j * 8];  // broadcast
        a0 += qf[j * 8 + 0] * b2f(kk[0]);
        a1 += qf[j * 8 + 1] * b2f(kk[1]);
        a2 += qf[j * 8 + 2] * b2f(kk[2]);
        a3 += qf[j * 8 + 3] * b2f(kk[3]);
        a0 += qf[j * 8 + 4] * b2f(kk[4]);
        a1 += qf[j * 8 + 5] * b2f(kk[5]);
        a2 += qf[j * 8 + 6] * b2f(kk[6]);
        a3 += qf[j * 8 + 7] * b2f(kk[7]);
      }
      float a = (a0 + a1) + (a2 + a3) + mb[s];
      myrow[s] = a;
      rmax = fmaxf(rmax, a);
    }
    // PV with fused exp
    f32x4 acc[16];
#pragma unroll
    for (int dq = 0; dq < 16; ++dq) acc[dq] = (f32x4){0.f, 0.f, 0.f, 0.f};
    float sum = 0.f;
    for (int s = 0; s < NS; ++s) {
      float p = __expf(myrow[s] - rmax);
      sum += p;
#pragma unroll
      for (int dq = 0; dq < 16; ++dq) {
        f32x4 vv = *(const f32x4*)&Vs[s * 64 + dq * 4];  // broadcast
        acc[dq] += p * vv;
      }
    }
    float inv = 1.f / sum;
    u16* op = out + ((size_t)b * NS + t) * ND + h * 64;
#pragma unroll
    for (int j = 0; j < 8; ++j) {
      u16x8 o;
#pragma unroll
      for (int e = 0; e < 8; ++e) {
        int d = j * 8 + e;
        o[e] = f2b(acc[d >> 2][d & 3] * inv);
      }
      *(u16x8*)(op + j * 8) = o;
    }
  }
}

// ---------------------------------------------------------------------------
// x = LN(x + r) * g + b ; writes f32 x and bf16 xb. One row per 128-thr block.
// ---------------------------------------------------------------------------
__global__ __launch_bounds__(128) void add_ln_kernel(float* __restrict__ x,
                                                     u16* __restrict__ xb,
                                                     const float* __restrict__ rsd,
                                                     const float* __restrict__ g,
                                                     const float* __restrict__ bb) {
  const int row = blockIdx.x;
  const int t = threadIdx.x;
  const size_t base = (size_t)row * ND + t * 4;
  float4 v = *(float4*)(x + base);
  float4 r = *(const float4*)(rsd + base);
  v.x += r.x; v.y += r.y; v.z += r.z; v.w += r.w;
  float s = (v.x + v.y) + (v.z + v.w);
  float q = (v.x * v.x + v.y * v.y) + (v.z * v.z + v.w * v.w);
#pragma unroll
  for (int off = 32; off; off >>= 1) {
    s += __shfl_down(s, off);
    q += __shfl_down(q, off);
  }
  __shared__ float sb[4];
  const int wid = t >> 6;
  if ((t & 63) == 0) { sb[wid * 2] = s; sb[wid * 2 + 1] = q; }
  __syncthreads();
  float ts = sb[0] + sb[2];
  float tq = sb[1] + sb[3];
  float mean = ts * (1.f / (float)ND);
  float var = tq * (1.f / (float)ND) - mean * mean;
  float rstd = rsqrtf(var + 1e-5f);
  float4 gg = *(const float4*)(g + t * 4);
  float4 bv = *(const float4*)(bb + t * 4);
  float o0 = (v.x - mean) * rstd * gg.x + bv.x;
  float o1 = (v.y - mean) * rstd * gg.y + bv.y;
  float o2 = (v.z - mean) * rstd * gg.z + bv.z;
  float o3 = (v.w - mean) * rstd * gg.w + bv.w;
  *(float4*)(x + base) = (float4){o0, o1, o2, o3};
  u16x4 ob = {f2b(o0), f2b(o1), f2b(o2), f2b(o3)};
  *(u16x4*)(xb + base) = ob;
}

// ---------------------------------------------------------------------------
// w2sum[d] = sum_o attn_w[o, D + d]   (s_q and attn_b cancel in the softmax)
// ---------------------------------------------------------------------------
__global__ __launch_bounds__(64) void w2sum_kernel(const float* __restrict__ attn_w,
                                                   float* __restrict__ w2sum) {
  int d = blockIdx.x * 64 + threadIdx.x;
  float s = 0.f;
  for (int o = 0; o < ND; ++o) s += attn_w[(size_t)o * 1024 + 512 + d];
  w2sum[d] = s;
}

// ---------------------------------------------------------------------------
// Pooling head: p = softmax_s(mask ? x[b,s].w2sum : -inf); out[b] = p @ x[b]
// 256 threads: wave-per-row dots (stride-64, conflict-free), coalesced output.
// ---------------------------------------------------------------------------
__global__ __launch_bounds__(256) void pool_kernel(const float* __restrict__ x,
                                                   const int* __restrict__ mask,
                                                   const float* __restrict__ w2sum,
                                                   float* __restrict__ out) {
  const int b = blockIdx.x;
  const int t = threadIdx.x;
  __shared__ float wsm[ND];
  __shared__ float sv[NS + 12];
  wsm[t] = w2sum[t];
  wsm[t + 256] = w2sum[t + 256];
  __syncthreads();
  const int wv = t >> 6, ln = t & 63;
  for (int s = wv; s < NS; s += 4) {
    const float* xr = x + ((size_t)b * NS + s) * ND;
    float acc = 0.f;
#pragma unroll
    for (int j = 0; j < 8; ++j) acc += xr[ln + j * 64] * wsm[ln + j * 64];
#pragma unroll
    for (int off = 32; off; off >>= 1) acc += __shfl_xor(acc, off);
    if (ln == 0) sv[s] = (mask[b * NS + s] != 0) ? acc : -INFINITY;
  }
  __syncthreads();
  float mx = -INFINITY;
  for (int s = 0; s < NS; ++s) mx = fmaxf(mx, sv[s]);  // broadcast
  if (t < NS) sv[t] = __expf(sv[t] - mx);
  __syncthreads();
  float sum = 0.f;
  for (int s = 0; s < NS; ++s) sum += sv[s];
  const float inv = 1.f / sum;
  float a0 = 0.f, a1 = 0.f;
  for (int s = 0; s < NS; ++s) {
    float p = sv[s];
    const float* xr = x + ((size_t)b * NS + s) * ND;
    a0 += p * xr[t];
    a1 += p * xr[t + 256];
  }
  out[(size_t)b * ND + t] = a0 * inv;
  out[(size_t)b * ND + t + 256] = a1 * inv;
}

// ---------------------------------------------------------------------------
extern "C" void kernel_launch(void* const* d_in, const int* in_sizes, int n_in,
                              void* d_out, int out_size, void* d_ws, size_t ws_size,
                              hipStream_t stream) {
  const int* mask = (const int*)d_in[0];
  const float* emb = (const float*)d_in[1];
  const float* in_proj_w = (const float*)d_in[2];
  const float* in_proj_b = (const float*)d_in[3];
  const float* out_proj_w = (const float*)d_in[4];
  const float* out_proj_b = (const float*)d_in[5];
  const float* lin1_w = (const float*)d_in[6];
  const float* lin1_b = (const float*)d_in[7];
  const float* lin2_w = (const float*)d_in[8];
  const float* lin2_b = (const float*)d_in[9];
  const float* ln1_w = (const float*)d_in[10];
  const float* ln1_b = (const float*)d_in[11];
  const float* ln2_w = (const float*)d_in[12];
  const float* ln2_b = (const float*)d_in[13];
  const float* attn_w = (const float*)d_in[14];
  // d_in[15] = attn_b: constant over softmax axis -> cancels; unused.

  char* wsb = (char*)d_ws;
  size_t off = 0;
  auto alloc = [&](size_t bytes) -> char* {
    char* p = wsb + off;
    off += (bytes + 255) & ~(size_t)255;
    return p;
  };
  float* x   = (float*)alloc((size_t)NM * ND * 4);
  u16* xb    = (u16*)alloc((size_t)NM * ND * 2);
  u16* wqkv  = (u16*)alloc((size_t)NL * 1536 * 512 * 2);
  u16* wout  = (u16*)alloc((size_t)NL * 512 * 512 * 2);
  u16* w1b   = (u16*)alloc((size_t)NL * 2048 * 512 * 2);
  u16* w2b   = (u16*)alloc((size_t)NL * 512 * 2048 * 2);
  float* w2s = (float*)alloc(ND * 4);
  size_t fixedEnd = off;

  int BC = 32;
  const int cands[4] = {256, 128, 64, 32};
  auto alup = [](size_t b) { return (b + 255) & ~(size_t)255; };
  for (int ci = 0; ci < 4; ++ci) {
    size_t Mc = (size_t)cands[ci] * NS;
    size_t need = fixedEnd + alup(Mc * 2048 * 2) + alup(Mc * 512 * 2) + alup(Mc * 512 * 4);
    if (need <= ws_size) { BC = cands[ci]; break; }
  }
  const size_t Mc = (size_t)BC * NS;
  u16* big    = (u16*)alloc(Mc * 2048 * 2);
  u16* bufA   = (u16*)alloc(Mc * 512 * 2);
  float* bufT = (float*)alloc(Mc * 512 * 4);

  cast_kernel<<<NL * 1536 * 512 / 1024, 256, 0, stream>>>(in_proj_w, wqkv);
  cast_kernel<<<NL * 512 * 512 / 1024, 256, 0, stream>>>(out_proj_w, wout);
  cast_kernel<<<NL * 2048 * 512 / 1024, 256, 0, stream>>>(lin1_w, w1b);
  cast_kernel<<<NL * 512 * 2048 / 1024, 256, 0, stream>>>(lin2_w, w2b);
  add_pe_kernel<<<NM * ND / 256, 256, 0, stream>>>(emb, x, xb);

  const int NC = NB / BC;
  for (int i = 0; i < NL; ++i) {
    for (int c = 0; c < NC; ++c) {
      float* xc = x + (size_t)c * Mc * ND;
      u16* xbc = xb + (size_t)c * Mc * ND;
      gemm_mfma<false, true><<<dim3(1536 / 128, Mc / 128), 256, 0, stream>>>(
          xbc, wqkv + (size_t)i * 1536 * 512, in_proj_b + i * 1536, nullptr, big, 1536, 512);
      attn_kernel<<<BC * NH, 128, 0, stream>>>(big, mask + (size_t)c * BC * NS, bufA);
      gemm_mfma<false, false><<<dim3(512 / 128, Mc / 128), 256, 0, stream>>>(
          bufA, wout + (size_t)i * 512 * 512, out_proj_b + i * 512, bufT, nullptr, 512, 512);
      add_ln_kernel<<<Mc, 128, 0, stream>>>(xc, xbc, bufT, ln1_w + i * 512, ln1_b + i * 512);
      gemm_mfma<true, true><<<dim3(2048 / 128, Mc / 128), 256, 0, stream>>>(
          xbc, w1b + (size_t)i * 2048 * 512, lin1_b + i * 2048, nullptr, big, 2048, 512);
      gemm_mfma<false, false><<<dim3(512 / 128, Mc / 128), 256, 0, stream>>>(
          big, w2b + (size_t)i * 512 * 2048, lin2_b + i * 512, bufT, nullptr, 512, 2048);
      add_ln_kernel<<<Mc, 128, 0, stream>>>(xc, xbc, bufT, ln2_w + i * 512, ln2_b + i * 512);
    }
  }

  w2sum_kernel<<<ND / 64, 64, 0, stream>>>(attn_w, w2s);
  pool_kernel<<<NB, 256, 0, stream>>>(x, mask, w2s, (float*)d_out);
}

// Round 4
// 2126.965 us; speedup vs baseline: 2.3296x; 1.1220x over previous
//
#include <hip/hip_runtime.h>
#include <math.h>

#define NB 256
#define NS 100
#define ND 512
#define NH 8
#define NDFF 2048
#define NL 4
#define NM (NB * NS)  // 25600 tokens

typedef unsigned short u16;
typedef unsigned short u16x4 __attribute__((ext_vector_type(4)));
typedef unsigned short u16x8 __attribute__((ext_vector_type(8)));
typedef __bf16 bf16x8 __attribute__((ext_vector_type(8)));
typedef float f32x4 __attribute__((ext_vector_type(4)));

__device__ __forceinline__ float b2f(u16 u) {
  unsigned v = ((unsigned)u) << 16;
  return __builtin_bit_cast(float, v);
}
__device__ __forceinline__ u16 f2b(float f) {
  unsigned u = __builtin_bit_cast(unsigned, f);
  u += 0x7fffu + ((u >> 16) & 1u);
  return (u16)(u >> 16);
}
// async global->LDS, 16B per lane; LDS dest is wave-uniform base (HW adds lane*16)
__device__ __forceinline__ void gload_lds16(const void* g, void* l) {
  __builtin_amdgcn_global_load_lds(
      (const __attribute__((address_space(1))) unsigned int*)g,
      (__attribute__((address_space(3))) unsigned int*)l, 16, 0, 0);
}

// ---------------------------------------------------------------------------
// f32 -> bf16 cast (weights)
// ---------------------------------------------------------------------------
__global__ __launch_bounds__(256) void cast_kernel(const float* __restrict__ in,
                                                   u16* __restrict__ out) {
  int i = blockIdx.x * 256 + threadIdx.x;
  float4 v = ((const float4*)in)[i];
  u16x4 o = {f2b(v.x), f2b(v.y), f2b(v.z), f2b(v.w)};
  ((u16x4*)out)[i] = o;
}

// ---------------------------------------------------------------------------
// x = emb + PE ; writes f32 x and bf16 mirror xb
// ---------------------------------------------------------------------------
__global__ __launch_bounds__(256) void add_pe_kernel(const float* __restrict__ emb,
                                                     float* __restrict__ x,
                                                     u16* __restrict__ xb) {
  int idx = blockIdx.x * 256 + threadIdx.x;
  int d = idx & (ND - 1);
  int s = (idx >> 9) % NS;
  float ang = (float)s * (float)(d & ~1) * (-4.6051701859880914f / (float)ND);
  float pe = (d & 1) ? __cosf(ang) : __sinf(ang);
  float v = emb[idx] + pe;
  x[idx] = v;
  xb[idx] = f2b(v);
}

// ---------------------------------------------------------------------------
// C = A @ W^T + bias (+R residual) (optional ReLU). A: MxK bf16, W: NxK bf16.
// 128x128 tile, BK=64, 4 waves (2x2). Linear LDS [128][64] via global_load_lds
// width=16 with PRE-SWIZZLED global source (rule #21 / m173): lane l fetches
// 16B-block (l&7)^(l>>3) of its row; ds_read applies blk ^= (row&7).
// -> every 16-lane phase hits 8 distinct bank-quads (2-way = free, m136).
// C/D: col = lane&15, row = (lane>>4)*4 + j   [verified rounds 2-3]
// ---------------------------------------------------------------------------
template <bool RELU, bool OUTBF16, bool RESID>
__global__ __launch_bounds__(256) void gemm_mfma(const u16* __restrict__ A,
                                                 const u16* __restrict__ W,
                                                 const float* __restrict__ bias,
                                                 const float* __restrict__ R,
                                                 float* __restrict__ Cf,
                                                 u16* __restrict__ Cb,
                                                 int N, int K) {
  __shared__ u16 As[128 * 64];
  __shared__ u16 Ws[128 * 64];
  const int t = threadIdx.x;
  const int lane = t & 63;
  const int wave = t >> 6;
  const int wr = wave >> 1, wc = wave & 1;
  const int m0 = blockIdx.y * 128, n0 = blockIdx.x * 128;

  // staging: chunk = wave + 4*i (8 rows each); lane l -> row l>>3, swz block
  const int srow = lane >> 3;               // 0..7
  const int sblk = (lane & 7) ^ srow;       // pre-swizzled 16B block
  const u16* gA = A + (size_t)(m0 + wave * 8 + srow) * K + sblk * 8;
  const u16* gW = W + (size_t)(n0 + wave * 8 + srow) * K + sblk * 8;
  u16* lA = As + wave * 512;
  u16* lW = Ws + wave * 512;

  f32x4 acc[4][4];
#pragma unroll
  for (int m = 0; m < 4; ++m)
#pragma unroll
    for (int n = 0; n < 4; ++n) acc[m][n] = (f32x4){0.f, 0.f, 0.f, 0.f};

  const int lg = lane >> 4;  // k-group 0..3
  const int li = lane & 15;  // fragment row/col
  const int l7 = li & 7;

  for (int k0 = 0; k0 < K; k0 += 64) {
    __syncthreads();  // previous tile fully consumed
#pragma unroll
    for (int i = 0; i < 4; ++i) {
      gload_lds16(gA + k0 + (size_t)(32 * i) * K, lA + i * 2048);
      gload_lds16(gW + k0 + (size_t)(32 * i) * K, lW + i * 2048);
    }
    __syncthreads();  // drains vmcnt -> tile resident
#pragma unroll
    for (int h = 0; h < 2; ++h) {
      bf16x8 af[4], bf_[4];
#pragma unroll
      for (int m = 0; m < 4; ++m) {
        int row = wr * 64 + m * 16 + li;
        af[m] = __builtin_bit_cast(
            bf16x8, *(const u16x8*)&As[row * 64 + (((h << 2) + lg) ^ l7) * 8]);
      }
#pragma unroll
      for (int n = 0; n < 4; ++n) {
        int row = wc * 64 + n * 16 + li;
        bf_[n] = __builtin_bit_cast(
            bf16x8, *(const u16x8*)&Ws[row * 64 + (((h << 2) + lg) ^ l7) * 8]);
      }
#pragma unroll
      for (int m = 0; m < 4; ++m)
#pragma unroll
        for (int n = 0; n < 4; ++n)
          acc[m][n] = __builtin_amdgcn_mfma_f32_16x16x32_bf16(af[m], bf_[n], acc[m][n], 0, 0, 0);
    }
  }

#pragma unroll
  for (int m = 0; m < 4; ++m) {
    int row = m0 + wr * 64 + m * 16 + lg * 4;
#pragma unroll
    for (int n = 0; n < 4; ++n) {
      int col = n0 + wc * 64 + n * 16 + li;
      float bv = bias[col];
#pragma unroll
      for (int j = 0; j < 4; ++j) {
        float v = acc[m][n][j] + bv;
        if (RESID) v += R[(size_t)(row + j) * N + col];
        if (RELU) v = fmaxf(v, 0.f);
        if (OUTBF16) Cb[(size_t)(row + j) * N + col] = f2b(v);
        else Cf[(size_t)(row + j) * N + col] = v;
      }
    }
  }
}

// ---------------------------------------------------------------------------
// Attention per (b,h), thread-per-query, ONLINE softmax fully in registers
// (T13 deferred rescale, thr=8). LDS: K bf16 (12.8K) + V f32 (25.6K) + mask
// -> 38.9 KB -> 4 blocks/CU. One barrier. s=0 is always unmasked (lengths>=1)
// so the running max is finite before any masked key (no -inf - -inf NaN).
// ---------------------------------------------------------------------------
__global__ __launch_bounds__(128) void attn_kernel(const u16* __restrict__ qkv,
                                                   const int* __restrict__ mask,
                                                   u16* __restrict__ out) {
  const int bh = blockIdx.x;
  const int b = bh >> 3, h = bh & 7;
  __shared__ u16 Ksb[NS * 64];   // 12.8 KB
  __shared__ float Vs[NS * 64];  // 25.6 KB
  __shared__ float mb[NS + 4];
  const int t = threadIdx.x;
  const u16* base = qkv + (size_t)b * NS * 1536 + h * 64;

  for (int e = t; e < NS * 16; e += 128) {
    int s = e >> 4, d4 = (e & 15) << 2;
    *(u16x4*)&Ksb[s * 64 + d4] = *(const u16x4*)(base + (size_t)s * 1536 + 512 + d4);
    u16x4 vv = *(const u16x4*)(base + (size_t)s * 1536 + 1024 + d4);
    Vs[s * 64 + d4 + 0] = b2f(vv[0]);
    Vs[s * 64 + d4 + 1] = b2f(vv[1]);
    Vs[s * 64 + d4 + 2] = b2f(vv[2]);
    Vs[s * 64 + d4 + 3] = b2f(vv[3]);
  }
  if (t < NS) mb[t] = (mask[b * NS + t] == 0) ? -INFINITY : 0.f;

  float qf[64];
  if (t < NS) {
    const u16* gq = base + (size_t)t * 1536;
#pragma unroll
    for (int j = 0; j < 8; ++j) {
      u16x8 qq = *(const u16x8*)(gq + j * 8);
#pragma unroll
      for (int e = 0; e < 8; ++e) qf[j * 8 + e] = b2f(qq[e]) * 0.125f;
    }
  }
  __syncthreads();  // staging complete (the only barrier)
  if (t >= NS) return;

  f32x4 acc[16];
#pragma unroll
  for (int dq = 0; dq < 16; ++dq) acc[dq] = (f32x4){0.f, 0.f, 0.f, 0.f};
  float m = -INFINITY, sum = 0.f;

  for (int s = 0; s < NS; ++s) {
    float a0 = 0.f, a1 = 0.f, a2 = 0.f, a3 = 0.f;
#pragma unroll
    for (int j = 0; j < 8; ++j) {
      u16x8 kk = *(const u16x8*)&Ksb[s * 64 + j * 8];  // broadcast
      a0 += qf[j * 8 + 0] * b2f(kk[0]);
      a1 += qf[j * 8 + 1] * b2f(kk[1]);
      a2 += qf[j * 8 + 2] * b2f(kk[2]);
      a3 += qf[j * 8 + 3] * b2f(kk[3]);
      a0 += qf[j * 8 + 4] * b2f(kk[4]);
      a1 += qf[j * 8 + 5] * b2f(kk[5]);
      a2 += qf[j * 8 + 6] * b2f(kk[6]);
      a3 += qf[j * 8 + 7] * b2f(kk[7]);
    }
    float a = (a0 + a1) + (a2 + a3) + mb[s];
    if (a > m + 8.f) {  // deferred rescale (rare; exec-masked)
      float cs = __expf(m - a);  // first hit: exp(-inf)=0 zeroes the (zero) state
      sum *= cs;
#pragma unroll
      for (int dq = 0; dq < 16; ++dq) acc[dq] *= cs;
      m = a;
    }
    float p = __expf(a - m);  // masked: exp(-inf - finite) = 0
    sum += p;
#pragma unroll
    for (int dq = 0; dq < 16; ++dq)
      acc[dq] += p * *(const f32x4*)&Vs[s * 64 + dq * 4];  // broadcast
  }
  float inv = 1.f / sum;
  u16* op = out + ((size_t)b * NS + t) * ND + h * 64;
#pragma unroll
  for (int j = 0; j < 8; ++j) {
    u16x8 o;
#pragma unroll
    for (int e = 0; e < 8; ++e) {
      int d = j * 8 + e;
      o[e] = f2b(acc[d >> 2][d & 3] * inv);
    }
    *(u16x8*)(op + j * 8) = o;
  }
}

// ---------------------------------------------------------------------------
// x = LN(in) * g + b ; in already holds x + proj (residual fused in GEMM).
// Writes f32 x and bf16 xb. One row per 128-thr block.
// ---------------------------------------------------------------------------
__global__ __launch_bounds__(128) void add_ln_kernel(const float* __restrict__ in,
                                                     float* __restrict__ x,
                                                     u16* __restrict__ xb,
                                                     const float* __restrict__ g,
                                                     const float* __restrict__ bb) {
  const int row = blockIdx.x;
  const int t = threadIdx.x;
  const size_t base = (size_t)row * ND + t * 4;
  float4 v = *(const float4*)(in + base);
  float s = (v.x + v.y) + (v.z + v.w);
  float q = (v.x * v.x + v.y * v.y) + (v.z * v.z + v.w * v.w);
#pragma unroll
  for (int off = 32; off; off >>= 1) {
    s += __shfl_down(s, off);
    q += __shfl_down(q, off);
  }
  __shared__ float sb[4];
  const int wid = t >> 6;
  if ((t & 63) == 0) { sb[wid * 2] = s; sb[wid * 2 + 1] = q; }
  __syncthreads();
  float ts = sb[0] + sb[2];
  float tq = sb[1] + sb[3];
  float mean = ts * (1.f / (float)ND);
  float var = tq * (1.f / (float)ND) - mean * mean;
  float rstd = rsqrtf(var + 1e-5f);
  float4 gg = *(const float4*)(g + t * 4);
  float4 bv = *(const float4*)(bb + t * 4);
  float o0 = (v.x - mean) * rstd * gg.x + bv.x;
  float o1 = (v.y - mean) * rstd * gg.y + bv.y;
  float o2 = (v.z - mean) * rstd * gg.z + bv.z;
  float o3 = (v.w - mean) * rstd * gg.w + bv.w;
  *(float4*)(x + base) = (float4){o0, o1, o2, o3};
  u16x4 ob = {f2b(o0), f2b(o1), f2b(o2), f2b(o3)};
  *(u16x4*)(xb + base) = ob;
}

// ---------------------------------------------------------------------------
// w2sum[d] = sum_o attn_w[o, D + d]   (s_q and attn_b cancel in the softmax)
// ---------------------------------------------------------------------------
__global__ __launch_bounds__(64) void w2sum_kernel(const float* __restrict__ attn_w,
                                                   float* __restrict__ w2sum) {
  int d = blockIdx.x * 64 + threadIdx.x;
  float s = 0.f;
  for (int o = 0; o < ND; ++o) s += attn_w[(size_t)o * 1024 + 512 + d];
  w2sum[d] = s;
}

// ---------------------------------------------------------------------------
// Pooling head: p = softmax_s(mask ? x[b,s].w2sum : -inf); out[b] = p @ x[b]
// ---------------------------------------------------------------------------
__global__ __launch_bounds__(256) void pool_kernel(const float* __restrict__ x,
                                                   const int* __restrict__ mask,
                                                   const float* __restrict__ w2sum,
                                                   float* __restrict__ out) {
  const int b = blockIdx.x;
  const int t = threadIdx.x;
  __shared__ float wsm[ND];
  __shared__ float sv[NS + 12];
  wsm[t] = w2sum[t];
  wsm[t + 256] = w2sum[t + 256];
  __syncthreads();
  const int wv = t >> 6, ln = t & 63;
  for (int s = wv; s < NS; s += 4) {
    const float* xr = x + ((size_t)b * NS + s) * ND;
    float acc = 0.f;
#pragma unroll
    for (int j = 0; j < 8; ++j) acc += xr[ln + j * 64] * wsm[ln + j * 64];
#pragma unroll
    for (int off = 32; off; off >>= 1) acc += __shfl_xor(acc, off);
    if (ln == 0) sv[s] = (mask[b * NS + s] != 0) ? acc : -INFINITY;
  }
  __syncthreads();
  float mx = -INFINITY;
  for (int s = 0; s < NS; ++s) mx = fmaxf(mx, sv[s]);  // broadcast
  if (t < NS) sv[t] = __expf(sv[t] - mx);
  __syncthreads();
  float sum = 0.f;
  for (int s = 0; s < NS; ++s) sum += sv[s];
  const float inv = 1.f / sum;
  float a0 = 0.f, a1 = 0.f;
  for (int s = 0; s < NS; ++s) {
    float p = sv[s];
    const float* xr = x + ((size_t)b * NS + s) * ND;
    a0 += p * xr[t];
    a1 += p * xr[t + 256];
  }
  out[(size_t)b * ND + t] = a0 * inv;
  out[(size_t)b * ND + t + 256] = a1 * inv;
}

// ---------------------------------------------------------------------------
extern "C" void kernel_launch(void* const* d_in, const int* in_sizes, int n_in,
                              void* d_out, int out_size, void* d_ws, size_t ws_size,
                              hipStream_t stream) {
  const int* mask = (const int*)d_in[0];
  const float* emb = (const float*)d_in[1];
  const float* in_proj_w = (const float*)d_in[2];
  const float* in_proj_b = (const float*)d_in[3];
  const float* out_proj_w = (const float*)d_in[4];
  const float* out_proj_b = (const float*)d_in[5];
  const float* lin1_w = (const float*)d_in[6];
  const float* lin1_b = (const float*)d_in[7];
  const float* lin2_w = (const float*)d_in[8];
  const float* lin2_b = (const float*)d_in[9];
  const float* ln1_w = (const float*)d_in[10];
  const float* ln1_b = (const float*)d_in[11];
  const float* ln2_w = (const float*)d_in[12];
  const float* ln2_b = (const float*)d_in[13];
  const float* attn_w = (const float*)d_in[14];
  // d_in[15] = attn_b: constant over softmax axis -> cancels; unused.

  char* wsb = (char*)d_ws;
  size_t off = 0;
  auto alloc = [&](size_t bytes) -> char* {
    char* p = wsb + off;
    off += (bytes + 255) & ~(size_t)255;
    return p;
  };
  float* x   = (float*)alloc((size_t)NM * ND * 4);
  u16* xb    = (u16*)alloc((size_t)NM * ND * 2);
  u16* wqkv  = (u16*)alloc((size_t)NL * 1536 * 512 * 2);
  u16* wout  = (u16*)alloc((size_t)NL * 512 * 512 * 2);
  u16* w1b   = (u16*)alloc((size_t)NL * 2048 * 512 * 2);
  u16* w2b   = (u16*)alloc((size_t)NL * 512 * 2048 * 2);
  float* w2s = (float*)alloc(ND * 4);
  size_t fixedEnd = off;

  int BC = 32;
  const int cands[4] = {256, 128, 64, 32};
  auto alup = [](size_t b) { return (b + 255) & ~(size_t)255; };
  for (int ci = 0; ci < 4; ++ci) {
    size_t Mc = (size_t)cands[ci] * NS;
    size_t need = fixedEnd + alup(Mc * 2048 * 2) + alup(Mc * 512 * 2) + alup(Mc * 512 * 4);
    if (need <= ws_size) { BC = cands[ci]; break; }
  }
  const size_t Mc = (size_t)BC * NS;
  u16* big    = (u16*)alloc(Mc * 2048 * 2);
  u16* bufA   = (u16*)alloc(Mc * 512 * 2);
  float* bufT = (float*)alloc(Mc * 512 * 4);

  cast_kernel<<<NL * 1536 * 512 / 1024, 256, 0, stream>>>(in_proj_w, wqkv);
  cast_kernel<<<NL * 512 * 512 / 1024, 256, 0, stream>>>(out_proj_w, wout);
  cast_kernel<<<NL * 2048 * 512 / 1024, 256, 0, stream>>>(lin1_w, w1b);
  cast_kernel<<<NL * 512 * 2048 / 1024, 256, 0, stream>>>(lin2_w, w2b);
  add_pe_kernel<<<NM * ND / 256, 256, 0, stream>>>(emb, x, xb);

  const int NC = NB / BC;
  for (int i = 0; i < NL; ++i) {
    for (int c = 0; c < NC; ++c) {
      float* xc = x + (size_t)c * Mc * ND;
      u16* xbc = xb + (size_t)c * Mc * ND;
      gemm_mfma<false, true, false><<<dim3(1536 / 128, Mc / 128), 256, 0, stream>>>(
          xbc, wqkv + (size_t)i * 1536 * 512, in_proj_b + i * 1536, nullptr, nullptr, big, 1536, 512);
      attn_kernel<<<BC * NH, 128, 0, stream>>>(big, mask + (size_t)c * BC * NS, bufA);
      gemm_mfma<false, false, true><<<dim3(512 / 128, Mc / 128), 256, 0, stream>>>(
          bufA, wout + (size_t)i * 512 * 512, out_proj_b + i * 512, xc, bufT, nullptr, 512, 512);
      add_ln_kernel<<<Mc, 128, 0, stream>>>(bufT, xc, xbc, ln1_w + i * 512, ln1_b + i * 512);
      gemm_mfma<true, true, false><<<dim3(2048 / 128, Mc / 128), 256, 0, stream>>>(
          xbc, w1b + (size_t)i * 2048 * 512, lin1_b + i * 2048, nullptr, nullptr, big, 2048, 512);
      gemm_mfma<false, false, true><<<dim3(512 / 128, Mc / 128), 256, 0, stream>>>(
          big, w2b + (size_t)i * 512 * 2048, lin2_b + i * 512, xc, bufT, nullptr, 512, 2048);
      add_ln_kernel<<<Mc, 128, 0, stream>>>(bufT, xc, xbc, ln2_w + i * 512, ln2_b + i * 512);
    }
  }

  w2sum_kernel<<<ND / 64, 64, 0, stream>>>(attn_w, w2s);
  pool_kernel<<<NB, 256, 0, stream>>>(x, mask, w2s, (float*)d_out);
}